// Round 9
// baseline (639.015 us; speedup 1.0000x reference)
//
#include <hip/hip_runtime.h>

// B=64, C=2, N=1024, T=13, D=256
// out: [B,N,N] fp32 = 268 MB; ws: centered ranks as int8 [B,N,D] = 16 MB

typedef __attribute__((ext_vector_type(4))) int i32x4;

__device__ __forceinline__ void load_lds16(const void* g, void* l) {
  __builtin_amdgcn_global_load_lds(
      (const __attribute__((address_space(1))) void*)g,
      (__attribute__((address_space(3))) void*)l, 16, 0, 0);
}

// ---------------------------------------------------------------------------
// K1: conv (bcnt,dct->bnd) + time-LayerNorm + Spearman rank -> (rank-128) int8
// Round-6 structure (wave-local 32-bit bitonic sort + 8-step LDS search).
// NEW: __launch_bounds__(256, 8) forces VGPR<=64 (was 68, just past the
// 64-reg occupancy cliff, m69) -> 2x resident waves to hide the sort's
// serial shfl latency chain (R8 counters: VALUBusy 56%, Occupancy 32%).
// ---------------------------------------------------------------------------
__global__ __launch_bounds__(256, 8) void conv_rank_kernel(
    const float* __restrict__ x, const float* __restrict__ w,
    const float* __restrict__ cb, const float* __restrict__ tg,
    const float* __restrict__ tb, signed char* __restrict__ ranks)
{
  int grp = blockIdx.x;              // 16384 = 64 batches * 256 row-groups
  int b = grp >> 8;
  int n0 = (grp & 255) << 2;         // 4 rows, one per wave
  int tid = threadIdx.x;
  int wave = tid >> 6, lane = tid & 63;
  int row = b * 1024 + n0 + wave;

  __shared__ float xs[4][26];
  __shared__ unsigned int ws[4][256];

  if (tid < 104) {
    int c = tid / 52, rem = tid - c * 52;   // rem = r*13 + t
    int r = rem / 13, t = rem - r * 13;
    xs[r][c * 13 + t] = x[((size_t)(b * 2 + c) * 1024 + n0 + r) * 13 + t];
  }
  __syncthreads();

  // conv: 4 dims d = i*64+lane; w row = 26 floats = 13 float2
  float accv[4];
  #pragma unroll
  for (int i = 0; i < 4; ++i) {
    int d = i * 64 + lane;
    const float2* wp = (const float2*)(w + d * 26);
    float a = cb[d];
    #pragma unroll
    for (int u = 0; u < 13; ++u) {
      float2 w2 = wp[u];
      a += w2.x * xs[wave][2 * u] + w2.y * xs[wave][2 * u + 1];
    }
    accv[i] = a;
  }

  // time layernorm over D=256: in-lane 4 + 6-level butterfly
  float s1 = accv[0] + accv[1] + accv[2] + accv[3];
  float s2 = accv[0] * accv[0] + accv[1] * accv[1] +
             accv[2] * accv[2] + accv[3] * accv[3];
  #pragma unroll
  for (int o = 1; o < 64; o <<= 1) {
    s1 += __shfl_xor(s1, o);
    s2 += __shfl_xor(s2, o);
  }
  float mu = s1 * (1.0f / 256.0f);
  float var = s2 * (1.0f / 256.0f) - mu * mu;
  float rs = rsqrtf(var + 1e-5f);

  // monotone sortable u32 keys
  unsigned int key[4], okey[4];
  #pragma unroll
  for (int i = 0; i < 4; ++i) {
    int d = i * 64 + lane;
    float val = (accv[i] - mu) * rs * tg[d] + tb[d];
    unsigned int u = __float_as_uint(val);
    key[i] = (u & 0x80000000u) ? ~u : (u | 0x80000000u);
    okey[i] = key[i];
  }

  // bitonic sort ascending over e = i*64+lane (value-only, tie-safe)
  #pragma unroll
  for (int k = 2; k <= 256; k <<= 1) {
    #pragma unroll
    for (int j = k >> 1; j > 0; j >>= 1) {
      if (j < 64) {
        #pragma unroll
        for (int i = 0; i < 4; ++i) {
          unsigned int pk = __shfl_xor(key[i], j);
          int e = i * 64 + lane;
          bool km = ((e & j) == 0) == ((e & k) == 0);
          unsigned int mn = key[i] < pk ? key[i] : pk;
          unsigned int mx = key[i] < pk ? pk : key[i];
          key[i] = km ? mn : mx;
        }
      } else {
        int di = j >> 6;             // 1 or 2 (register exchange across i)
        #pragma unroll
        for (int i = 0; i < 4; ++i) {
          if ((i & di) == 0) {
            int ip = i + di;
            int e = i * 64 + lane;   // low element of the pair
            bool up = ((e & k) == 0);
            unsigned int a = key[i], bb = key[ip];
            unsigned int mn = a < bb ? a : bb;
            unsigned int mx = a < bb ? bb : a;
            key[i]  = up ? mn : mx;
            key[ip] = up ? mx : mn;
          }
        }
      }
    }
  }

  // sorted keys -> wave-private LDS; rank = lower_bound(okey)
  #pragma unroll
  for (int i = 0; i < 4; ++i) ws[wave][i * 64 + lane] = key[i];
  __syncthreads();
  int pos[4] = {0, 0, 0, 0};
  #pragma unroll
  for (int s = 128; s > 0; s >>= 1) {
    #pragma unroll
    for (int i = 0; i < 4; ++i)
      pos[i] += (ws[wave][pos[i] + s - 1] < okey[i]) ? s : 0;
  }
  #pragma unroll
  for (int i = 0; i < 4; ++i)
    ranks[(size_t)row * 256 + i * 64 + lane] = (signed char)(pos[i] - 128);
}

// ---------------------------------------------------------------------------
// K2 (fused, ROUND-7 measured-best ~72us by ledger): per batch S = R R^T
// (int8 MFMA, exact i32), adj = |S-64|*inv_den, LayerNorm over node axis +
// ReLU + store. 8 waves, 32 rows x 1024 cols. Row-major LDS with XOR chunk
// swizzle; contiguous global staging segments (4x fewer line-touches).
// (R8's wave-private dbuf regressed +46us: 141KB LDS -> 1 block/CU.)
// ---------------------------------------------------------------------------
__global__ __launch_bounds__(512, 4) void corr_ln_kernel(
    const signed char* __restrict__ ranks, const float* __restrict__ sg,
    const float* __restrict__ sb, float* __restrict__ out)
{
  // XCD-chunked swizzle: each XCD gets 256 consecutive work items = 8 batches
  int bid = blockIdx.x;
  int blk = (bid & 7) * 256 + (bid >> 3);
  int b  = blk >> 5;
  int n0 = (blk & 31) << 5;           // 32 rows
  const signed char* R = ranks + (size_t)b * 1024 * 256;
  float* O = out + ((size_t)b * 1024 + n0) * 1024;

  __shared__ __align__(16) signed char As[32 * 256];   // [r][c'], c' = c ^ (r&7)
  __shared__ __align__(16) signed char Bs[1024 * 64];  // [row][q'], q' = q ^ (row&3)
  __shared__ float red[8][64];                         // [wave][32 sum | 32 sq]
  __shared__ float stats[2][32];                       // mu, rs per row

  int tid = threadIdx.x;
  int wave = tid >> 6, lane = tid & 63;
  int fr = lane & 15, quad = lane >> 4;
  int cw = wave << 7;                 // 128-col strip per wave

  // stage A once (32 rows x 256B, full K): row = tid>>4, dest chunk c' = tid&15,
  // global chunk c = c' ^ (row&7). Per wave: 4 rows x 256B contiguous.
  {
    int r = tid >> 4, cp = tid & 15;
    int c = cp ^ (r & 7);
    load_lds16(R + (size_t)(n0 + r) * 256 + c * 16, As + tid * 16);
  }

  i32x4 acc[2][8] = {};

  for (int kt = 0; kt < 4; ++kt) {
    // stage B chunk: row = i*128 + tid>>2, dest q' = tid&3, global q = q'^(row&3)
    // Per wave-instr: 16 rows x 64B contiguous segments (permuted 16B chunks).
    #pragma unroll
    for (int i = 0; i < 8; ++i) {
      int r = i * 128 + (tid >> 2);
      int q = (tid & 3) ^ (r & 3);
      load_lds16(R + (size_t)r * 256 + kt * 64 + q * 16,
                 Bs + i * 8192 + tid * 16);
    }
    __syncthreads();   // drains vmcnt (covers As on kt=0)

    int csw = ((kt * 4 + quad) ^ (fr & 7)) << 4;   // swizzled A chunk offset
    i32x4 af0 = *(const i32x4*)(As + fr * 256 + csw);
    i32x4 af1 = *(const i32x4*)(As + (16 + fr) * 256 + csw);
    #pragma unroll
    for (int ni = 0; ni < 8; ++ni) {
      int rowb = cw + ni * 16 + fr;
      i32x4 bf = *(const i32x4*)(Bs + rowb * 64 + ((quad ^ (rowb & 3)) << 4));
      acc[0][ni] = __builtin_amdgcn_mfma_i32_16x16x64_i8(af0, bf, acc[0][ni], 0, 0, 0);
      acc[1][ni] = __builtin_amdgcn_mfma_i32_16x16x64_i8(af1, bf, acc[1][ni], 0, 0, 0);
    }
    __syncthreads();
  }

  // adj = |S - 64| * inv_den  (exact int S)
  float nrm = sqrtf(1398080.0f);
  float inv_den = 1.0f / (nrm * nrm + 1e-8f);

  // LN pass 1: per-row partial sums over this wave's 128-col strip
  float s[2][4], q[2][4];
  #pragma unroll
  for (int mi = 0; mi < 2; ++mi) {
    #pragma unroll
    for (int v = 0; v < 4; ++v) {
      float ss = 0.0f, qq = 0.0f;
      #pragma unroll
      for (int ni = 0; ni < 8; ++ni) {
        float a = fabsf((float)(acc[mi][ni][v] - 64)) * inv_den;
        ss += a; qq += a * a;
      }
      #pragma unroll
      for (int o = 8; o > 0; o >>= 1) {   // reduce across the 16-lane group
        ss += __shfl_xor(ss, o);
        qq += __shfl_xor(qq, o);
      }
      s[mi][v] = ss; q[mi][v] = qq;
    }
  }
  if (fr == 0) {
    #pragma unroll
    for (int mi = 0; mi < 2; ++mi)
      #pragma unroll
      for (int v = 0; v < 4; ++v) {
        int r = mi * 16 + quad * 4 + v;
        red[wave][r] = s[mi][v];
        red[wave][32 + r] = q[mi][v];
      }
  }
  __syncthreads();

  if (tid < 32) {
    float su = 0.0f, sq = 0.0f;
    #pragma unroll
    for (int ww = 0; ww < 8; ++ww) { su += red[ww][tid]; sq += red[ww][32 + tid]; }
    float mu = su * (1.0f / 1024.0f);
    float var = sq * (1.0f / 1024.0f) - mu * mu;
    stats[0][tid] = mu;
    stats[1][tid] = rsqrtf(var + 1e-5f);
  }
  __syncthreads();

  // pass 2: normalize + ReLU + store
  float gv[8], bv[8];
  #pragma unroll
  for (int ni = 0; ni < 8; ++ni) {
    int col = cw + ni * 16 + fr;
    gv[ni] = sg[col];
    bv[ni] = sb[col];
  }
  #pragma unroll
  for (int mi = 0; mi < 2; ++mi) {
    #pragma unroll
    for (int v = 0; v < 4; ++v) {
      int r = mi * 16 + quad * 4 + v;
      float mu = stats[0][r], rs = stats[1][r];
      float* orow = O + (size_t)r * 1024;
      #pragma unroll
      for (int ni = 0; ni < 8; ++ni) {
        float a = fabsf((float)(acc[mi][ni][v] - 64)) * inv_den;
        orow[cw + ni * 16 + fr] = fmaxf(0.0f, (a - mu) * rs * gv[ni] + bv[ni]);
      }
    }
  }
}

extern "C" void kernel_launch(void* const* d_in, const int* in_sizes, int n_in,
                              void* d_out, int out_size, void* d_ws, size_t ws_size,
                              hipStream_t stream) {
  const float* x  = (const float*)d_in[0];
  const float* w  = (const float*)d_in[1];
  const float* cb = (const float*)d_in[2];
  const float* tg = (const float*)d_in[3];
  const float* tb = (const float*)d_in[4];
  const float* sg = (const float*)d_in[5];
  const float* sb = (const float*)d_in[6];
  float* out = (float*)d_out;
  signed char* ranks = (signed char*)d_ws;  // 64*1024*256 = 16 MB

  conv_rank_kernel<<<16384, 256, 0, stream>>>(x, w, cb, tg, tb, ranks);
  corr_ln_kernel<<<2048, 512, 0, stream>>>(ranks, sg, sb, out);
}

// Round 10
// 463.195 us; speedup vs baseline: 1.3796x; 1.3796x over previous
//
#include <hip/hip_runtime.h>

// B=64, C=2, N=1024, T=13, D=256
// out: [B,N,N] fp32 = 268 MB; ws: centered ranks as int8 [B,N,D] = 16 MB

typedef __attribute__((ext_vector_type(4))) int i32x4;

__device__ __forceinline__ void load_lds16(const void* g, void* l) {
  __builtin_amdgcn_global_load_lds(
      (const __attribute__((address_space(1))) void*)g,
      (__attribute__((address_space(3))) void*)l, 16, 0, 0);
}

// ---------------------------------------------------------------------------
// K1: conv (bcnt,dct->bnd) + time-LayerNorm + Spearman rank -> (rank-128) int8
// Round-6 structure (wave-local 32-bit bitonic sort + 8-step LDS search).
// NO forced launch bound (R9's (256,8) caused 1.1GB scratch spill, 349us).
// NEW: okey[] manually spilled to wave-private LDS across the sort phase --
// trims the sort-phase live set by 4 regs (was 68, cliff at 64, m69).
// Post-sort block barrier removed (ws/os are wave-private; lgkmcnt suffices).
// ---------------------------------------------------------------------------
__global__ __launch_bounds__(256) void conv_rank_kernel(
    const float* __restrict__ x, const float* __restrict__ w,
    const float* __restrict__ cb, const float* __restrict__ tg,
    const float* __restrict__ tb, signed char* __restrict__ ranks)
{
  int grp = blockIdx.x;              // 16384 = 64 batches * 256 row-groups
  int b = grp >> 8;
  int n0 = (grp & 255) << 2;         // 4 rows, one per wave
  int tid = threadIdx.x;
  int wave = tid >> 6, lane = tid & 63;
  int row = b * 1024 + n0 + wave;

  __shared__ float xs[4][26];
  __shared__ unsigned int ws[4][256];   // sorted keys (wave-private)
  __shared__ unsigned int os[4][256];   // original keys (wave-private)

  if (tid < 104) {
    int c = tid / 52, rem = tid - c * 52;   // rem = r*13 + t
    int r = rem / 13, t = rem - r * 13;
    xs[r][c * 13 + t] = x[((size_t)(b * 2 + c) * 1024 + n0 + r) * 13 + t];
  }
  __syncthreads();

  // conv: 4 dims d = i*64+lane; w row = 26 floats = 13 float2
  float accv[4];
  #pragma unroll
  for (int i = 0; i < 4; ++i) {
    int d = i * 64 + lane;
    const float2* wp = (const float2*)(w + d * 26);
    float a = cb[d];
    #pragma unroll
    for (int u = 0; u < 13; ++u) {
      float2 w2 = wp[u];
      a += w2.x * xs[wave][2 * u] + w2.y * xs[wave][2 * u + 1];
    }
    accv[i] = a;
  }

  // time layernorm over D=256: in-lane 4 + 6-level butterfly
  float s1 = accv[0] + accv[1] + accv[2] + accv[3];
  float s2 = accv[0] * accv[0] + accv[1] * accv[1] +
             accv[2] * accv[2] + accv[3] * accv[3];
  #pragma unroll
  for (int o = 1; o < 64; o <<= 1) {
    s1 += __shfl_xor(s1, o);
    s2 += __shfl_xor(s2, o);
  }
  float mu = s1 * (1.0f / 256.0f);
  float var = s2 * (1.0f / 256.0f) - mu * mu;
  float rs = rsqrtf(var + 1e-5f);

  // monotone sortable u32 keys; original keys -> LDS (manual spill: frees
  // 4 VGPRs across the 36-substep sort)
  unsigned int key[4];
  #pragma unroll
  for (int i = 0; i < 4; ++i) {
    int d = i * 64 + lane;
    float val = (accv[i] - mu) * rs * tg[d] + tb[d];
    unsigned int u = __float_as_uint(val);
    key[i] = (u & 0x80000000u) ? ~u : (u | 0x80000000u);
    os[wave][i * 64 + lane] = key[i];
  }

  // bitonic sort ascending over e = i*64+lane (value-only, tie-safe)
  #pragma unroll
  for (int k = 2; k <= 256; k <<= 1) {
    #pragma unroll
    for (int j = k >> 1; j > 0; j >>= 1) {
      if (j < 64) {
        #pragma unroll
        for (int i = 0; i < 4; ++i) {
          unsigned int pk = __shfl_xor(key[i], j);
          int e = i * 64 + lane;
          bool km = ((e & j) == 0) == ((e & k) == 0);
          unsigned int mn = key[i] < pk ? key[i] : pk;
          unsigned int mx = key[i] < pk ? pk : key[i];
          key[i] = km ? mn : mx;
        }
      } else {
        int di = j >> 6;             // 1 or 2 (register exchange across i)
        #pragma unroll
        for (int i = 0; i < 4; ++i) {
          if ((i & di) == 0) {
            int ip = i + di;
            int e = i * 64 + lane;   // low element of the pair
            bool up = ((e & k) == 0);
            unsigned int a = key[i], bb = key[ip];
            unsigned int mn = a < bb ? a : bb;
            unsigned int mx = a < bb ? bb : a;
            key[i]  = up ? mn : mx;
            key[ip] = up ? mx : mn;
          }
        }
      }
    }
  }

  // sorted keys -> wave-private LDS; rank = lower_bound(original key).
  // No block barrier: ws/os rows are wave-private (lgkmcnt ordering suffices).
  #pragma unroll
  for (int i = 0; i < 4; ++i) ws[wave][i * 64 + lane] = key[i];
  unsigned int ok[4];
  #pragma unroll
  for (int i = 0; i < 4; ++i) ok[i] = os[wave][i * 64 + lane];
  int pos[4] = {0, 0, 0, 0};
  #pragma unroll
  for (int s = 128; s > 0; s >>= 1) {
    #pragma unroll
    for (int i = 0; i < 4; ++i)
      pos[i] += (ws[wave][pos[i] + s - 1] < ok[i]) ? s : 0;
  }
  #pragma unroll
  for (int i = 0; i < 4; ++i)
    ranks[(size_t)row * 256 + i * 64 + lane] = (signed char)(pos[i] - 128);
}

// ---------------------------------------------------------------------------
// K2 (fused, round-7 structure): per batch S = R R^T (int8 MFMA, exact i32),
// adj = |S-64|*inv_den, LayerNorm over node axis + ReLU + store.
// 8 waves, 32 rows x 1024 cols. Row-major LDS with XOR chunk swizzle;
// contiguous global staging segments (4x fewer line-touches).
// ---------------------------------------------------------------------------
__global__ __launch_bounds__(512, 4) void corr_ln_kernel(
    const signed char* __restrict__ ranks, const float* __restrict__ sg,
    const float* __restrict__ sb, float* __restrict__ out)
{
  // XCD-chunked swizzle: each XCD gets 256 consecutive work items = 8 batches
  int bid = blockIdx.x;
  int blk = (bid & 7) * 256 + (bid >> 3);
  int b  = blk >> 5;
  int n0 = (blk & 31) << 5;           // 32 rows
  const signed char* R = ranks + (size_t)b * 1024 * 256;
  float* O = out + ((size_t)b * 1024 + n0) * 1024;

  __shared__ __align__(16) signed char As[32 * 256];   // [r][c'], c' = c ^ (r&7)
  __shared__ __align__(16) signed char Bs[1024 * 64];  // [row][q'], q' = q ^ (row&3)
  __shared__ float red[8][64];                         // [wave][32 sum | 32 sq]
  __shared__ float stats[2][32];                       // mu, rs per row

  int tid = threadIdx.x;
  int wave = tid >> 6, lane = tid & 63;
  int fr = lane & 15, quad = lane >> 4;
  int cw = wave << 7;                 // 128-col strip per wave

  // stage A once (32 rows x 256B, full K): row = tid>>4, dest chunk c' = tid&15,
  // global chunk c = c' ^ (row&7). Per wave: 4 rows x 256B contiguous.
  {
    int r = tid >> 4, cp = tid & 15;
    int c = cp ^ (r & 7);
    load_lds16(R + (size_t)(n0 + r) * 256 + c * 16, As + tid * 16);
  }

  i32x4 acc[2][8] = {};

  for (int kt = 0; kt < 4; ++kt) {
    // stage B chunk: row = i*128 + tid>>2, dest q' = tid&3, global q = q'^(row&3)
    // Per wave-instr: 16 rows x 64B contiguous segments (permuted 16B chunks).
    #pragma unroll
    for (int i = 0; i < 8; ++i) {
      int r = i * 128 + (tid >> 2);
      int q = (tid & 3) ^ (r & 3);
      load_lds16(R + (size_t)r * 256 + kt * 64 + q * 16,
                 Bs + i * 8192 + tid * 16);
    }
    __syncthreads();   // drains vmcnt (covers As on kt=0)

    int csw = ((kt * 4 + quad) ^ (fr & 7)) << 4;   // swizzled A chunk offset
    i32x4 af0 = *(const i32x4*)(As + fr * 256 + csw);
    i32x4 af1 = *(const i32x4*)(As + (16 + fr) * 256 + csw);
    #pragma unroll
    for (int ni = 0; ni < 8; ++ni) {
      int rowb = cw + ni * 16 + fr;
      i32x4 bf = *(const i32x4*)(Bs + rowb * 64 + ((quad ^ (rowb & 3)) << 4));
      acc[0][ni] = __builtin_amdgcn_mfma_i32_16x16x64_i8(af0, bf, acc[0][ni], 0, 0, 0);
      acc[1][ni] = __builtin_amdgcn_mfma_i32_16x16x64_i8(af1, bf, acc[1][ni], 0, 0, 0);
    }
    __syncthreads();
  }

  // adj = |S - 64| * inv_den  (exact int S)
  float nrm = sqrtf(1398080.0f);
  float inv_den = 1.0f / (nrm * nrm + 1e-8f);

  // LN pass 1: per-row partial sums over this wave's 128-col strip
  float s[2][4], q[2][4];
  #pragma unroll
  for (int mi = 0; mi < 2; ++mi) {
    #pragma unroll
    for (int v = 0; v < 4; ++v) {
      float ss = 0.0f, qq = 0.0f;
      #pragma unroll
      for (int ni = 0; ni < 8; ++ni) {
        float a = fabsf((float)(acc[mi][ni][v] - 64)) * inv_den;
        ss += a; qq += a * a;
      }
      #pragma unroll
      for (int o = 8; o > 0; o >>= 1) {   // reduce across the 16-lane group
        ss += __shfl_xor(ss, o);
        qq += __shfl_xor(qq, o);
      }
      s[mi][v] = ss; q[mi][v] = qq;
    }
  }
  if (fr == 0) {
    #pragma unroll
    for (int mi = 0; mi < 2; ++mi)
      #pragma unroll
      for (int v = 0; v < 4; ++v) {
        int r = mi * 16 + quad * 4 + v;
        red[wave][r] = s[mi][v];
        red[wave][32 + r] = q[mi][v];
      }
  }
  __syncthreads();

  if (tid < 32) {
    float su = 0.0f, sq = 0.0f;
    #pragma unroll
    for (int ww = 0; ww < 8; ++ww) { su += red[ww][tid]; sq += red[ww][32 + tid]; }
    float mu = su * (1.0f / 1024.0f);
    float var = sq * (1.0f / 1024.0f) - mu * mu;
    stats[0][tid] = mu;
    stats[1][tid] = rsqrtf(var + 1e-5f);
  }
  __syncthreads();

  // pass 2: normalize + ReLU + store
  float gv[8], bv[8];
  #pragma unroll
  for (int ni = 0; ni < 8; ++ni) {
    int col = cw + ni * 16 + fr;
    gv[ni] = sg[col];
    bv[ni] = sb[col];
  }
  #pragma unroll
  for (int mi = 0; mi < 2; ++mi) {
    #pragma unroll
    for (int v = 0; v < 4; ++v) {
      int r = mi * 16 + quad * 4 + v;
      float mu = stats[0][r], rs = stats[1][r];
      float* orow = O + (size_t)r * 1024;
      #pragma unroll
      for (int ni = 0; ni < 8; ++ni) {
        float a = fabsf((float)(acc[mi][ni][v] - 64)) * inv_den;
        orow[cw + ni * 16 + fr] = fmaxf(0.0f, (a - mu) * rs * gv[ni] + bv[ni]);
      }
    }
  }
}

extern "C" void kernel_launch(void* const* d_in, const int* in_sizes, int n_in,
                              void* d_out, int out_size, void* d_ws, size_t ws_size,
                              hipStream_t stream) {
  const float* x  = (const float*)d_in[0];
  const float* w  = (const float*)d_in[1];
  const float* cb = (const float*)d_in[2];
  const float* tg = (const float*)d_in[3];
  const float* tb = (const float*)d_in[4];
  const float* sg = (const float*)d_in[5];
  const float* sb = (const float*)d_in[6];
  float* out = (float*)d_out;
  signed char* ranks = (signed char*)d_ws;  // 64*1024*256 = 16 MB

  conv_rank_kernel<<<16384, 256, 0, stream>>>(x, w, cb, tg, tb, ranks);
  corr_ln_kernel<<<2048, 512, 0, stream>>>(ranks, sg, sb, out);
}